// Round 1
// baseline (1174.953 us; speedup 1.0000x reference)
//
#include <hip/hip_runtime.h>

#define HID 64
#define NCLS 16
#define NCENT 3
#define NCENTS (NCLS * NCENT)

static inline int ceil_div(int a, int b) { return (a + b - 1) / b; }

// ---- CSR build ----------------------------------------------------------

__global__ void k_deg(const int* __restrict__ dst, int* __restrict__ deg, int E) {
    int e = blockIdx.x * blockDim.x + threadIdx.x;
    if (e < E) atomicAdd(&deg[dst[e]], 1);
}

__global__ void k_dinv(const int* __restrict__ deg, float* __restrict__ dinv, int N) {
    int i = blockIdx.x * blockDim.x + threadIdx.x;
    if (i < N) dinv[i] = rsqrtf((float)(deg[i] + 1));  // +1 self loop, always >=1
}

// Offsets need not be in node order for correctness; one atomic per node.
__global__ void k_rowstart(const int* __restrict__ deg, int* __restrict__ rs,
                           int* __restrict__ counter, int N) {
    int i = blockIdx.x * blockDim.x + threadIdx.x;
    if (i < N) rs[i] = atomicAdd(counter, deg[i]);
}

__global__ void k_fill(const int* __restrict__ src, const int* __restrict__ dst,
                       const int* __restrict__ rs, int* __restrict__ cursor,
                       const float* __restrict__ dinv,
                       int* __restrict__ col, float* __restrict__ enorm, int E) {
    int e = blockIdx.x * blockDim.x + threadIdx.x;
    if (e < E) {
        int d = dst[e], s = src[e];
        int p = rs[d] + atomicAdd(&cursor[d], 1);
        col[p] = s;
        enorm[p] = dinv[s] * dinv[d];
    }
}

// ---- dense GEMM: out[N,64] = A[N,K] @ W[K,64] ---------------------------
// wave per row; lane = output feature; W staged in LDS; row broadcast via shfl.

template <int K>
__global__ void k_gemm(const float* __restrict__ A, const float* __restrict__ W,
                       float* __restrict__ out, int N) {
    __shared__ float Wl[K * HID];
    for (int i = threadIdx.x; i < K * HID; i += blockDim.x) Wl[i] = W[i];
    __syncthreads();
    int row = blockIdx.x * (blockDim.x >> 6) + (threadIdx.x >> 6);
    int lane = threadIdx.x & 63;
    if (row >= N) return;
    const float* a = A + (size_t)row * K;
    float r0 = a[lane];
    float r1 = (K == 128) ? a[lane + 64] : 0.0f;
    float acc = 0.0f;
#pragma unroll
    for (int k = 0; k < 64; k++) acc = fmaf(__shfl(r0, k), Wl[k * HID + lane], acc);
    if (K == 128) {
#pragma unroll
        for (int k = 0; k < 64; k++) acc = fmaf(__shfl(r1, k), Wl[(k + 64) * HID + lane], acc);
    }
    out[(size_t)row * HID + lane] = acc;
}

// ---- aggregation: out[i] = dinv_i^2 * t[i] + sum_{e: dst=e->i} norm_e * t[src_e]
//      + bias, optional relu.  wave per dst node, lane = feature.

__global__ void k_agg(const float* __restrict__ tin, float* __restrict__ out,
                      const int* __restrict__ rs, const int* __restrict__ deg,
                      const int* __restrict__ col, const float* __restrict__ enorm,
                      const float* __restrict__ dinv, const float* __restrict__ bias,
                      int N, int relu) {
    int node = blockIdx.x * (blockDim.x >> 6) + (threadIdx.x >> 6);
    int lane = threadIdx.x & 63;
    if (node >= N) return;
    float di = dinv[node];
    float acc = di * di * tin[(size_t)node * HID + lane];  // self loop
    int beg = rs[node];
    int cnt = deg[node];
    for (int e = 0; e < cnt; e++) {
        int s = col[beg + e];        // wave-uniform -> broadcast load
        float w = enorm[beg + e];
        acc = fmaf(w, tin[(size_t)s * HID + lane], acc);  // coalesced 256B row
    }
    acc += bias[lane];
    if (relu) acc = fmaxf(acc, 0.0f);
    out[(size_t)node * HID + lane] = acc;
}

// ---- fused mean-pool + centroid-distance head ---------------------------
// batch is sorted; one block (4 waves) per graph; binary-search node range.

__global__ void k_pool_head(const float* __restrict__ h, const int* __restrict__ batch,
                            const float* __restrict__ cent, const float* __restrict__ rbias,
                            float* __restrict__ out, int N) {
    int g = blockIdx.x;
    // lower_bound(batch, g) and lower_bound(batch, g+1)
    int lo = 0, hi = N;
    while (lo < hi) { int mid = (lo + hi) >> 1; if (batch[mid] < g) lo = mid + 1; else hi = mid; }
    int s = lo;
    lo = 0; hi = N;
    while (lo < hi) { int mid = (lo + hi) >> 1; if (batch[mid] < g + 1) lo = mid + 1; else hi = mid; }
    int e = lo;

    __shared__ float part[4][HID];
    __shared__ float embS[HID];
    __shared__ float dS[NCENTS];
    __shared__ float dpcS[NCLS];

    int lane = threadIdx.x & 63, wid = threadIdx.x >> 6;
    float acc = 0.0f;
    for (int i = s + wid; i < e; i += 4) acc += h[(size_t)i * HID + lane];
    part[wid][lane] = acc;
    __syncthreads();
    if (wid == 0) {
        float v = part[0][lane] + part[1][lane] + part[2][lane] + part[3][lane];
        embS[lane] = v / fmaxf((float)(e - s), 1.0f);
    }
    __syncthreads();
    if (threadIdx.x < NCENTS) {
        const float* c = cent + threadIdx.x * HID;
        float d = 0.0f;
        for (int k = 0; k < HID; k++) { float df = embS[k] - c[k]; d = fmaf(df, df, d); }
        dS[threadIdx.x] = d;
    }
    __syncthreads();
    if (threadIdx.x < NCLS) {
        float m = fminf(dS[threadIdx.x * 3],
                        fminf(dS[threadIdx.x * 3 + 1], dS[threadIdx.x * 3 + 2]));
        dpcS[threadIdx.x] = m;
        out[g * (NCLS + 1) + threadIdx.x] = -m;
    }
    __syncthreads();
    if (threadIdx.x == 0) {
        float m = dpcS[0];
        for (int i = 1; i < NCLS; i++) m = fminf(m, dpcS[i]);
        out[g * (NCLS + 1) + NCLS] = m - rbias[0];
    }
}

// ---- launch -------------------------------------------------------------

extern "C" void kernel_launch(void* const* d_in, const int* in_sizes, int n_in,
                              void* d_out, int out_size, void* d_ws, size_t ws_size,
                              hipStream_t stream) {
    const float* x    = (const float*)d_in[0];
    const int*   ei   = (const int*)d_in[1];   // [2, E]: row0 = src, row1 = dst
    const int*   bat  = (const int*)d_in[2];
    const float* W1   = (const float*)d_in[3];
    const float* b1   = (const float*)d_in[4];
    const float* W2   = (const float*)d_in[5];
    const float* b2   = (const float*)d_in[6];
    const float* W3   = (const float*)d_in[7];
    const float* b3   = (const float*)d_in[8];
    const float* cent = (const float*)d_in[9];
    const float* rb   = (const float*)d_in[10];
    float* out = (float*)d_out;

    const int N = in_sizes[0] / 128;
    const int E = in_sizes[1] / 2;

    char* p = (char*)d_ws;
    float* A     = (float*)p; p += (size_t)N * HID * 4;
    float* Bb    = (float*)p; p += (size_t)N * HID * 4;
    float* dinv  = (float*)p; p += (size_t)N * 4;
    int*   col   = (int*)p;   p += (size_t)E * 4;
    float* enorm = (float*)p; p += (size_t)E * 4;
    int*   rs    = (int*)p;   p += (size_t)N * 4;
    // zeroed region: deg[N] | cursor[N] | counter[1]  (one memset)
    int*   deg   = (int*)p;   p += (size_t)N * 4;
    int*   cur   = (int*)p;   p += (size_t)N * 4;
    int*   cnt_  = (int*)p;   p += 4;

    hipMemsetAsync(deg, 0, ((size_t)2 * N + 1) * 4, stream);

    k_deg<<<ceil_div(E, 256), 256, 0, stream>>>(ei + E, deg, E);
    k_dinv<<<ceil_div(N, 256), 256, 0, stream>>>(deg, dinv, N);
    k_rowstart<<<ceil_div(N, 256), 256, 0, stream>>>(deg, rs, cnt_, N);
    k_fill<<<ceil_div(E, 256), 256, 0, stream>>>(ei, ei + E, rs, cur, dinv, col, enorm, E);

    const int rpb = 4;  // 256-thread blocks = 4 waves = 4 rows
    k_gemm<128><<<ceil_div(N, rpb), 256, 0, stream>>>(x, W1, A, N);
    k_agg<<<ceil_div(N, rpb), 256, 0, stream>>>(A, Bb, rs, deg, col, enorm, dinv, b1, N, 1);
    k_gemm<64><<<ceil_div(N, rpb), 256, 0, stream>>>(Bb, W2, A, N);
    k_agg<<<ceil_div(N, rpb), 256, 0, stream>>>(A, Bb, rs, deg, col, enorm, dinv, b2, N, 1);
    k_gemm<64><<<ceil_div(N, rpb), 256, 0, stream>>>(Bb, W3, A, N);
    k_agg<<<ceil_div(N, rpb), 256, 0, stream>>>(A, Bb, rs, deg, col, enorm, dinv, b3, N, 0);

    k_pool_head<<<1024, 256, 0, stream>>>(Bb, bat, cent, rb, out, N);
}

// Round 2
// 555.171 us; speedup vs baseline: 2.1164x; 2.1164x over previous
//
#include <hip/hip_runtime.h>

#define HID 64
#define NCLS 16
#define NCENT 3
#define NCENTS (NCLS * NCENT)

static inline int ceil_div(int a, int b) { return (a + b - 1) / b; }

// ---- CSR build ----------------------------------------------------------

__global__ void k_deg(const int* __restrict__ dst, int* __restrict__ deg, int E) {
    int e = blockIdx.x * blockDim.x + threadIdx.x;
    if (e < E) atomicAdd(&deg[dst[e]], 1);
}

__global__ void k_dinv(const int* __restrict__ deg, float* __restrict__ dinv, int N) {
    int i = blockIdx.x * blockDim.x + threadIdx.x;
    if (i < N) dinv[i] = rsqrtf((float)(deg[i] + 1));  // +1 self loop, always >=1
}

// Offsets need not be in node order for correctness; one atomic per node.
__global__ void k_rowstart(const int* __restrict__ deg, int* __restrict__ rs,
                           int* __restrict__ counter, int N) {
    int i = blockIdx.x * blockDim.x + threadIdx.x;
    if (i < N) rs[i] = atomicAdd(counter, deg[i]);
}

__global__ void k_fill(const int* __restrict__ src, const int* __restrict__ dst,
                       const int* __restrict__ rs, int* __restrict__ cursor,
                       const float* __restrict__ dinv,
                       int* __restrict__ col, float* __restrict__ enorm, int E) {
    int e = blockIdx.x * blockDim.x + threadIdx.x;
    if (e < E) {
        int d = dst[e], s = src[e];
        int p = rs[d] + atomicAdd(&cursor[d], 1);
        col[p] = s;
        enorm[p] = dinv[s] * dinv[d];
    }
}

// ---- dense GEMM: out[N,64] = A[N,K] @ W[K,64] ---------------------------
// 64-row tile / block (256 thr as 16x16); each thread computes 4 rows x 4 cols.
// K processed in 64-wide chunks; W-chunk + A-tile staged in LDS.
// As padded to 68 floats/row: A-read banks (4*(4ty+i)+k)%32 -> conflict-free,
// and 68*4=272 B row stride keeps float4 staging 16B-aligned.

template <int K>
__global__ __launch_bounds__(256) void k_gemm(const float* __restrict__ A,
                                              const float* __restrict__ W,
                                              float* __restrict__ out, int N) {
    __shared__ float Ws[64 * HID];
    __shared__ float As[64][68];
    const int tx = threadIdx.x & 15;   // col quad
    const int ty = threadIdx.x >> 4;   // row quad
    const int row0 = blockIdx.x * 64;

    float acc[4][4] = {};

    for (int k0 = 0; k0 < K; k0 += 64) {
        if (k0 > 0) __syncthreads();  // protect previous chunk's reads
        // stage W[k0..k0+63][0..63]  (1024 float4, coalesced)
        for (int i = threadIdx.x; i < 64 * 16; i += 256)
            ((float4*)Ws)[i] = ((const float4*)(W + (size_t)k0 * HID))[i];
        // stage A[row0..row0+63][k0..k0+63]
        for (int i = threadIdx.x; i < 64 * 16; i += 256) {
            int r = i >> 4, c = i & 15;
            int row = row0 + r;
            float4 v = {0.f, 0.f, 0.f, 0.f};
            if (row < N) v = *(const float4*)(A + (size_t)row * K + k0 + 4 * c);
            *(float4*)&As[r][4 * c] = v;
        }
        __syncthreads();
#pragma unroll 4
        for (int k = 0; k < 64; k++) {
            float4 w = *(const float4*)&Ws[k * HID + 4 * tx];
#pragma unroll
            for (int i = 0; i < 4; i++) {
                float a = As[4 * ty + i][k];
                acc[i][0] = fmaf(a, w.x, acc[i][0]);
                acc[i][1] = fmaf(a, w.y, acc[i][1]);
                acc[i][2] = fmaf(a, w.z, acc[i][2]);
                acc[i][3] = fmaf(a, w.w, acc[i][3]);
            }
        }
    }
#pragma unroll
    for (int i = 0; i < 4; i++) {
        int row = row0 + 4 * ty + i;
        if (row < N) {
            float4 v = {acc[i][0], acc[i][1], acc[i][2], acc[i][3]};
            *(float4*)&out[(size_t)row * HID + 4 * tx] = v;
        }
    }
}

// ---- aggregation: out[i] = dinv_i^2 * t[i] + sum_{e: dst->i} norm_e * t[src_e]
//      + bias, optional relu.  16-lane group per node, lane = float4 of feats;
//      edge loop unrolled x4 -> 4 independent 256B gathers in flight.

__global__ void k_agg(const float* __restrict__ tin, float* __restrict__ out,
                      const int* __restrict__ rs, const int* __restrict__ deg,
                      const int* __restrict__ col, const float* __restrict__ enorm,
                      const float* __restrict__ dinv, const float* __restrict__ bias,
                      int N, int relu) {
    int grp = (blockIdx.x * blockDim.x + threadIdx.x) >> 4;
    int l = threadIdx.x & 15;
    if (grp >= N) return;
    int node = grp;
    float di = dinv[node];
    float4 t = ((const float4*)(tin + (size_t)node * HID))[l];
    float s2 = di * di;
    float ax = s2 * t.x, ay = s2 * t.y, az = s2 * t.z, aw = s2 * t.w;

    int beg = rs[node];
    int cnt = deg[node];
    int e = 0;
    for (; e + 4 <= cnt; e += 4) {
        int s0 = col[beg + e], s1 = col[beg + e + 1];
        int sA = col[beg + e + 2], sB = col[beg + e + 3];
        float w0 = enorm[beg + e], w1 = enorm[beg + e + 1];
        float w2 = enorm[beg + e + 2], w3 = enorm[beg + e + 3];
        float4 v0 = ((const float4*)(tin + (size_t)s0 * HID))[l];
        float4 v1 = ((const float4*)(tin + (size_t)s1 * HID))[l];
        float4 v2 = ((const float4*)(tin + (size_t)sA * HID))[l];
        float4 v3 = ((const float4*)(tin + (size_t)sB * HID))[l];
        ax = fmaf(w0, v0.x, ax); ay = fmaf(w0, v0.y, ay); az = fmaf(w0, v0.z, az); aw = fmaf(w0, v0.w, aw);
        ax = fmaf(w1, v1.x, ax); ay = fmaf(w1, v1.y, ay); az = fmaf(w1, v1.z, az); aw = fmaf(w1, v1.w, aw);
        ax = fmaf(w2, v2.x, ax); ay = fmaf(w2, v2.y, ay); az = fmaf(w2, v2.z, az); aw = fmaf(w2, v2.w, aw);
        ax = fmaf(w3, v3.x, ax); ay = fmaf(w3, v3.y, ay); az = fmaf(w3, v3.z, az); aw = fmaf(w3, v3.w, aw);
    }
    for (; e < cnt; e++) {
        int s = col[beg + e];
        float w = enorm[beg + e];
        float4 v = ((const float4*)(tin + (size_t)s * HID))[l];
        ax = fmaf(w, v.x, ax); ay = fmaf(w, v.y, ay); az = fmaf(w, v.z, az); aw = fmaf(w, v.w, aw);
    }
    float4 b = ((const float4*)bias)[l];
    ax += b.x; ay += b.y; az += b.z; aw += b.w;
    if (relu) {
        ax = fmaxf(ax, 0.f); ay = fmaxf(ay, 0.f);
        az = fmaxf(az, 0.f); aw = fmaxf(aw, 0.f);
    }
    float4 o = {ax, ay, az, aw};
    ((float4*)(out + (size_t)node * HID))[l] = o;
}

// ---- fused mean-pool + centroid-distance head ---------------------------
// batch is sorted; one block (4 waves) per graph; binary-search node range.

__global__ void k_pool_head(const float* __restrict__ h, const int* __restrict__ batch,
                            const float* __restrict__ cent, const float* __restrict__ rbias,
                            float* __restrict__ out, int N) {
    int g = blockIdx.x;
    int lo = 0, hi = N;
    while (lo < hi) { int mid = (lo + hi) >> 1; if (batch[mid] < g) lo = mid + 1; else hi = mid; }
    int s = lo;
    lo = 0; hi = N;
    while (lo < hi) { int mid = (lo + hi) >> 1; if (batch[mid] < g + 1) lo = mid + 1; else hi = mid; }
    int e = lo;

    __shared__ float part[4][HID];
    __shared__ float embS[HID];
    __shared__ float dS[NCENTS];
    __shared__ float dpcS[NCLS];

    int lane = threadIdx.x & 63, wid = threadIdx.x >> 6;
    float acc = 0.0f;
    for (int i = s + wid; i < e; i += 4) acc += h[(size_t)i * HID + lane];
    part[wid][lane] = acc;
    __syncthreads();
    if (wid == 0) {
        float v = part[0][lane] + part[1][lane] + part[2][lane] + part[3][lane];
        embS[lane] = v / fmaxf((float)(e - s), 1.0f);
    }
    __syncthreads();
    if (threadIdx.x < NCENTS) {
        const float* c = cent + threadIdx.x * HID;
        float d = 0.0f;
        for (int k = 0; k < HID; k++) { float df = embS[k] - c[k]; d = fmaf(df, df, d); }
        dS[threadIdx.x] = d;
    }
    __syncthreads();
    if (threadIdx.x < NCLS) {
        float m = fminf(dS[threadIdx.x * 3],
                        fminf(dS[threadIdx.x * 3 + 1], dS[threadIdx.x * 3 + 2]));
        dpcS[threadIdx.x] = m;
        out[g * (NCLS + 1) + threadIdx.x] = -m;
    }
    __syncthreads();
    if (threadIdx.x == 0) {
        float m = dpcS[0];
        for (int i = 1; i < NCLS; i++) m = fminf(m, dpcS[i]);
        out[g * (NCLS + 1) + NCLS] = m - rbias[0];
    }
}

// ---- launch -------------------------------------------------------------

extern "C" void kernel_launch(void* const* d_in, const int* in_sizes, int n_in,
                              void* d_out, int out_size, void* d_ws, size_t ws_size,
                              hipStream_t stream) {
    const float* x    = (const float*)d_in[0];
    const int*   ei   = (const int*)d_in[1];   // [2, E]: row0 = src, row1 = dst
    const int*   bat  = (const int*)d_in[2];
    const float* W1   = (const float*)d_in[3];
    const float* b1   = (const float*)d_in[4];
    const float* W2   = (const float*)d_in[5];
    const float* b2   = (const float*)d_in[6];
    const float* W3   = (const float*)d_in[7];
    const float* b3   = (const float*)d_in[8];
    const float* cent = (const float*)d_in[9];
    const float* rb   = (const float*)d_in[10];
    float* out = (float*)d_out;

    const int N = in_sizes[0] / 128;
    const int E = in_sizes[1] / 2;

    char* p = (char*)d_ws;
    float* A     = (float*)p; p += (size_t)N * HID * 4;
    float* Bb    = (float*)p; p += (size_t)N * HID * 4;
    float* dinv  = (float*)p; p += (size_t)N * 4;
    int*   col   = (int*)p;   p += (size_t)E * 4;
    float* enorm = (float*)p; p += (size_t)E * 4;
    int*   rs    = (int*)p;   p += (size_t)N * 4;
    // zeroed region: deg[N] | cursor[N] | counter[1]  (one memset)
    int*   deg   = (int*)p;   p += (size_t)N * 4;
    int*   cur   = (int*)p;   p += (size_t)N * 4;
    int*   cnt_  = (int*)p;   p += 4;

    hipMemsetAsync(deg, 0, ((size_t)2 * N + 1) * 4, stream);

    k_deg<<<ceil_div(E, 256), 256, 0, stream>>>(ei + E, deg, E);
    k_dinv<<<ceil_div(N, 256), 256, 0, stream>>>(deg, dinv, N);
    k_rowstart<<<ceil_div(N, 256), 256, 0, stream>>>(deg, rs, cnt_, N);
    k_fill<<<ceil_div(E, 256), 256, 0, stream>>>(ei, ei + E, rs, cur, dinv, col, enorm, E);

    // GEMM: 64-row tiles
    k_gemm<128><<<ceil_div(N, 64), 256, 0, stream>>>(x, W1, A, N);
    k_agg<<<ceil_div(N * 16, 256), 256, 0, stream>>>(A, Bb, rs, deg, col, enorm, dinv, b1, N, 1);
    k_gemm<64><<<ceil_div(N, 64), 256, 0, stream>>>(Bb, W2, A, N);
    k_agg<<<ceil_div(N * 16, 256), 256, 0, stream>>>(A, Bb, rs, deg, col, enorm, dinv, b2, N, 1);
    k_gemm<64><<<ceil_div(N, 64), 256, 0, stream>>>(Bb, W3, A, N);
    k_agg<<<ceil_div(N * 16, 256), 256, 0, stream>>>(A, Bb, rs, deg, col, enorm, dinv, b3, N, 0);

    k_pool_head<<<1024, 256, 0, stream>>>(Bb, bat, cent, rb, out, N);
}

// Round 3
// 549.187 us; speedup vs baseline: 2.1394x; 1.0109x over previous
//
#include <hip/hip_runtime.h>

#define HID 64
#define NCLS 16
#define NCENT 3
#define NCENTS (NCLS * NCENT)

static inline int ceil_div(int a, int b) { return (a + b - 1) / b; }

// ---- CSR build ----------------------------------------------------------

__global__ void k_deg(const int* __restrict__ dst, int* __restrict__ deg, int E) {
    int e = blockIdx.x * blockDim.x + threadIdx.x;
    if (e < E) atomicAdd(&deg[dst[e]], 1);
}

// dinv + row-start in one pass. Offsets need not be in node order for
// correctness (any disjoint packing works); one atomic per node.
__global__ void k_node_init(const int* __restrict__ deg, float* __restrict__ dinv,
                            int* __restrict__ rs, int* __restrict__ counter, int N) {
    int i = blockIdx.x * blockDim.x + threadIdx.x;
    if (i < N) {
        int dg = deg[i];
        dinv[i] = rsqrtf((float)(dg + 1));  // +1 self loop, always >=1
        rs[i] = atomicAdd(counter, dg);
    }
}

// Only `col` is scattered now (one 4B store per edge); norm is reconstructed
// in k_agg from dinv — halves the scattered-sector HBM write traffic.
__global__ void k_fill(const int* __restrict__ src, const int* __restrict__ dst,
                       const int* __restrict__ rs, int* __restrict__ cursor,
                       int* __restrict__ col, int E) {
    int e = blockIdx.x * blockDim.x + threadIdx.x;
    if (e < E) {
        int d = dst[e];
        int p = rs[d] + atomicAdd(&cursor[d], 1);
        col[p] = src[e];
    }
}

// ---- dense GEMM: out[N,64] = A[N,K] @ W[K,64] ---------------------------
// 64-row tile / block (256 thr as 16x16); each thread computes 4 rows x 4 cols.

template <int K>
__global__ __launch_bounds__(256) void k_gemm(const float* __restrict__ A,
                                              const float* __restrict__ W,
                                              float* __restrict__ out, int N) {
    __shared__ float Ws[64 * HID];
    __shared__ float As[64][68];
    const int tx = threadIdx.x & 15;   // col quad
    const int ty = threadIdx.x >> 4;   // row quad
    const int row0 = blockIdx.x * 64;

    float acc[4][4] = {};

    for (int k0 = 0; k0 < K; k0 += 64) {
        if (k0 > 0) __syncthreads();
        for (int i = threadIdx.x; i < 64 * 16; i += 256)
            ((float4*)Ws)[i] = ((const float4*)(W + (size_t)k0 * HID))[i];
        for (int i = threadIdx.x; i < 64 * 16; i += 256) {
            int r = i >> 4, c = i & 15;
            int row = row0 + r;
            float4 v = {0.f, 0.f, 0.f, 0.f};
            if (row < N) v = *(const float4*)(A + (size_t)row * K + k0 + 4 * c);
            *(float4*)&As[r][4 * c] = v;
        }
        __syncthreads();
#pragma unroll 4
        for (int k = 0; k < 64; k++) {
            float4 w = *(const float4*)&Ws[k * HID + 4 * tx];
#pragma unroll
            for (int i = 0; i < 4; i++) {
                float a = As[4 * ty + i][k];
                acc[i][0] = fmaf(a, w.x, acc[i][0]);
                acc[i][1] = fmaf(a, w.y, acc[i][1]);
                acc[i][2] = fmaf(a, w.z, acc[i][2]);
                acc[i][3] = fmaf(a, w.w, acc[i][3]);
            }
        }
    }
#pragma unroll
    for (int i = 0; i < 4; i++) {
        int row = row0 + 4 * ty + i;
        if (row < N) {
            float4 v = {acc[i][0], acc[i][1], acc[i][2], acc[i][3]};
            *(float4*)&out[(size_t)row * HID + 4 * tx] = v;
        }
    }
}

// ---- aggregation: out[i] = dinv_i^2 * t[i] + sum_{e: dst->i} dinv_s*dinv_i * t[s]
//      + bias, optional relu.  16-lane group per node, lane = float4 of feats;
//      edge loop unrolled x4 -> 4 independent 256B gathers in flight.

__global__ void k_agg(const float* __restrict__ tin, float* __restrict__ out,
                      const int* __restrict__ rs, const int* __restrict__ deg,
                      const int* __restrict__ col,
                      const float* __restrict__ dinv, const float* __restrict__ bias,
                      int N, int relu) {
    int node = (blockIdx.x * blockDim.x + threadIdx.x) >> 4;
    int l = threadIdx.x & 15;
    if (node >= N) return;
    float di = dinv[node];
    float4 t = ((const float4*)(tin + (size_t)node * HID))[l];
    float s2 = di * di;
    float ax = s2 * t.x, ay = s2 * t.y, az = s2 * t.z, aw = s2 * t.w;

    int beg = rs[node];
    int cnt = deg[node];
    int e = 0;
    for (; e + 4 <= cnt; e += 4) {
        int s0 = col[beg + e], s1 = col[beg + e + 1];
        int sA = col[beg + e + 2], sB = col[beg + e + 3];
        float w0 = dinv[s0] * di, w1 = dinv[s1] * di;
        float w2 = dinv[sA] * di, w3 = dinv[sB] * di;
        float4 v0 = ((const float4*)(tin + (size_t)s0 * HID))[l];
        float4 v1 = ((const float4*)(tin + (size_t)s1 * HID))[l];
        float4 v2 = ((const float4*)(tin + (size_t)sA * HID))[l];
        float4 v3 = ((const float4*)(tin + (size_t)sB * HID))[l];
        ax = fmaf(w0, v0.x, ax); ay = fmaf(w0, v0.y, ay); az = fmaf(w0, v0.z, az); aw = fmaf(w0, v0.w, aw);
        ax = fmaf(w1, v1.x, ax); ay = fmaf(w1, v1.y, ay); az = fmaf(w1, v1.z, az); aw = fmaf(w1, v1.w, aw);
        ax = fmaf(w2, v2.x, ax); ay = fmaf(w2, v2.y, ay); az = fmaf(w2, v2.z, az); aw = fmaf(w2, v2.w, aw);
        ax = fmaf(w3, v3.x, ax); ay = fmaf(w3, v3.y, ay); az = fmaf(w3, v3.z, az); aw = fmaf(w3, v3.w, aw);
    }
    for (; e < cnt; e++) {
        int s = col[beg + e];
        float w = dinv[s] * di;
        float4 v = ((const float4*)(tin + (size_t)s * HID))[l];
        ax = fmaf(w, v.x, ax); ay = fmaf(w, v.y, ay); az = fmaf(w, v.z, az); aw = fmaf(w, v.w, aw);
    }
    float4 b = ((const float4*)bias)[l];
    ax += b.x; ay += b.y; az += b.z; aw += b.w;
    if (relu) {
        ax = fmaxf(ax, 0.f); ay = fmaxf(ay, 0.f);
        az = fmaxf(az, 0.f); aw = fmaxf(aw, 0.f);
    }
    float4 o = {ax, ay, az, aw};
    ((float4*)(out + (size_t)node * HID))[l] = o;
}

// ---- fused mean-pool + centroid-distance head ---------------------------

__global__ void k_pool_head(const float* __restrict__ h, const int* __restrict__ batch,
                            const float* __restrict__ cent, const float* __restrict__ rbias,
                            float* __restrict__ out, int N) {
    int g = blockIdx.x;
    int lo = 0, hi = N;
    while (lo < hi) { int mid = (lo + hi) >> 1; if (batch[mid] < g) lo = mid + 1; else hi = mid; }
    int s = lo;
    lo = 0; hi = N;
    while (lo < hi) { int mid = (lo + hi) >> 1; if (batch[mid] < g + 1) lo = mid + 1; else hi = mid; }
    int e = lo;

    __shared__ float part[4][HID];
    __shared__ float embS[HID];
    __shared__ float dS[NCENTS];
    __shared__ float dpcS[NCLS];

    int lane = threadIdx.x & 63, wid = threadIdx.x >> 6;
    float acc = 0.0f;
    for (int i = s + wid; i < e; i += 4) acc += h[(size_t)i * HID + lane];
    part[wid][lane] = acc;
    __syncthreads();
    if (wid == 0) {
        float v = part[0][lane] + part[1][lane] + part[2][lane] + part[3][lane];
        embS[lane] = v / fmaxf((float)(e - s), 1.0f);
    }
    __syncthreads();
    if (threadIdx.x < NCENTS) {
        const float* c = cent + threadIdx.x * HID;
        float d = 0.0f;
        for (int k = 0; k < HID; k++) { float df = embS[k] - c[k]; d = fmaf(df, df, d); }
        dS[threadIdx.x] = d;
    }
    __syncthreads();
    if (threadIdx.x < NCLS) {
        float m = fminf(dS[threadIdx.x * 3],
                        fminf(dS[threadIdx.x * 3 + 1], dS[threadIdx.x * 3 + 2]));
        dpcS[threadIdx.x] = m;
        out[g * (NCLS + 1) + threadIdx.x] = -m;
    }
    __syncthreads();
    if (threadIdx.x == 0) {
        float m = dpcS[0];
        for (int i = 1; i < NCLS; i++) m = fminf(m, dpcS[i]);
        out[g * (NCLS + 1) + NCLS] = m - rbias[0];
    }
}

// ---- launch -------------------------------------------------------------

extern "C" void kernel_launch(void* const* d_in, const int* in_sizes, int n_in,
                              void* d_out, int out_size, void* d_ws, size_t ws_size,
                              hipStream_t stream) {
    const float* x    = (const float*)d_in[0];
    const int*   ei   = (const int*)d_in[1];   // [2, E]: row0 = src, row1 = dst
    const int*   bat  = (const int*)d_in[2];
    const float* W1   = (const float*)d_in[3];
    const float* b1   = (const float*)d_in[4];
    const float* W2   = (const float*)d_in[5];
    const float* b2   = (const float*)d_in[6];
    const float* W3   = (const float*)d_in[7];
    const float* b3   = (const float*)d_in[8];
    const float* cent = (const float*)d_in[9];
    const float* rb   = (const float*)d_in[10];
    float* out = (float*)d_out;

    const int N = in_sizes[0] / 128;
    const int E = in_sizes[1] / 2;

    char* p = (char*)d_ws;
    float* A     = (float*)p; p += (size_t)N * HID * 4;
    float* Bb    = (float*)p; p += (size_t)N * HID * 4;
    float* dinv  = (float*)p; p += (size_t)N * 4;
    int*   col   = (int*)p;   p += (size_t)E * 4;
    int*   rs    = (int*)p;   p += (size_t)N * 4;
    // zeroed region: deg[N] | cursor[N] | counter[1]  (one memset)
    int*   deg   = (int*)p;   p += (size_t)N * 4;
    int*   cur   = (int*)p;   p += (size_t)N * 4;
    int*   cnt_  = (int*)p;   p += 4;

    hipMemsetAsync(deg, 0, ((size_t)2 * N + 1) * 4, stream);

    k_deg<<<ceil_div(E, 256), 256, 0, stream>>>(ei + E, deg, E);
    k_node_init<<<ceil_div(N, 256), 256, 0, stream>>>(deg, dinv, rs, cnt_, N);
    k_fill<<<ceil_div(E, 256), 256, 0, stream>>>(ei, ei + E, rs, cur, col, E);

    k_gemm<128><<<ceil_div(N, 64), 256, 0, stream>>>(x, W1, A, N);
    k_agg<<<ceil_div(N * 16, 256), 256, 0, stream>>>(A, Bb, rs, deg, col, dinv, b1, N, 1);
    k_gemm<64><<<ceil_div(N, 64), 256, 0, stream>>>(Bb, W2, A, N);
    k_agg<<<ceil_div(N * 16, 256), 256, 0, stream>>>(A, Bb, rs, deg, col, dinv, b2, N, 1);
    k_gemm<64><<<ceil_div(N, 64), 256, 0, stream>>>(Bb, W3, A, N);
    k_agg<<<ceil_div(N * 16, 256), 256, 0, stream>>>(A, Bb, rs, deg, col, dinv, b3, N, 0);

    k_pool_head<<<1024, 256, 0, stream>>>(Bb, bat, cent, rb, out, N);
}

// Round 4
// 520.520 us; speedup vs baseline: 2.2573x; 1.0551x over previous
//
#include <hip/hip_runtime.h>

#define HID 64
#define NCLS 16
#define NCENT 3
#define NCENTS (NCLS * NCENT)
#define NPART 8

static inline int ceil_div(int a, int b) { return (a + b - 1) / b; }

// ---- CSR build (partition-colored: p = blockIdx&7 ~ XCD via round-robin) ----

__global__ void k_deg(const int* __restrict__ dst, int* __restrict__ deg,
                      int E, int partSize, int N) {
    int p = blockIdx.x & (NPART - 1);
    int e = (blockIdx.x >> 3) * blockDim.x + threadIdx.x;
    if (e >= E) return;
    int d = dst[e];
    int lo = p * partSize;
    if (d >= lo && d < lo + partSize) atomicAdd(&deg[d], 1);
}

// exclusive scan of deg -> rs (node-ordered), plus dinv. 1024 elems/block.

__global__ void k_scan1(const int* __restrict__ deg, int* __restrict__ bsum, int N) {
    __shared__ int ts[256];
    int t = threadIdx.x;
    int base = blockIdx.x * 1024 + t * 4;
    int s = 0;
#pragma unroll
    for (int j = 0; j < 4; j++) if (base + j < N) s += deg[base + j];
    ts[t] = s;
    __syncthreads();
    for (int off = 128; off > 0; off >>= 1) {
        if (t < off) ts[t] += ts[t + off];
        __syncthreads();
    }
    if (t == 0) bsum[blockIdx.x] = ts[0];
}

__global__ void k_scan2(int* __restrict__ bsum, int B) {
    if (threadIdx.x == 0 && blockIdx.x == 0) {
        int acc = 0;
        for (int i = 0; i < B; i++) { int v = bsum[i]; bsum[i] = acc; acc += v; }
    }
}

__global__ void k_scan3(const int* __restrict__ deg, const int* __restrict__ boff,
                        int* __restrict__ rs, float* __restrict__ dinv, int N) {
    __shared__ int ts[256];
    int t = threadIdx.x;
    int base = blockIdx.x * 1024 + t * 4;
    int v[4];
    int s = 0;
#pragma unroll
    for (int j = 0; j < 4; j++) {
        v[j] = (base + j < N) ? deg[base + j] : 0;
        s += v[j];
    }
    ts[t] = s;
    __syncthreads();
    for (int off = 1; off < 256; off <<= 1) {
        int x = (t >= off) ? ts[t - off] : 0;
        __syncthreads();
        ts[t] += x;
        __syncthreads();
    }
    int run = boff[blockIdx.x] + ts[t] - s;  // exclusive
#pragma unroll
    for (int j = 0; j < 4; j++) {
        if (base + j < N) {
            rs[base + j] = run;
            dinv[base + j] = rsqrtf((float)(v[j] + 1));  // +1 self loop
            run += v[j];
        }
    }
}

// rs monotone -> partition p writes land in compact col[rs[lo]..rs[hi]) window
// (~800 KB, L2-resident on the XCD that owns color p).

__global__ void k_fill(const int* __restrict__ src, const int* __restrict__ dst,
                       const int* __restrict__ rs, int* __restrict__ cursor,
                       int* __restrict__ col, int E, int partSize, int N) {
    int p = blockIdx.x & (NPART - 1);
    int e = (blockIdx.x >> 3) * blockDim.x + threadIdx.x;
    if (e >= E) return;
    int d = dst[e];
    int lo = p * partSize;
    if (d >= lo && d < lo + partSize) {
        int pos = rs[d] + atomicAdd(&cursor[d], 1);
        col[pos] = src[e];
    }
}

// ---- dense GEMM: out[N,64] = A[N,K] @ W[K,64] ---------------------------

template <int K>
__global__ __launch_bounds__(256) void k_gemm(const float* __restrict__ A,
                                              const float* __restrict__ W,
                                              float* __restrict__ out, int N) {
    __shared__ float Ws[64 * HID];
    __shared__ float As[64][68];
    const int tx = threadIdx.x & 15;
    const int ty = threadIdx.x >> 4;
    const int row0 = blockIdx.x * 64;

    float acc[4][4] = {};

    for (int k0 = 0; k0 < K; k0 += 64) {
        if (k0 > 0) __syncthreads();
        for (int i = threadIdx.x; i < 64 * 16; i += 256)
            ((float4*)Ws)[i] = ((const float4*)(W + (size_t)k0 * HID))[i];
        for (int i = threadIdx.x; i < 64 * 16; i += 256) {
            int r = i >> 4, c = i & 15;
            int row = row0 + r;
            float4 v = {0.f, 0.f, 0.f, 0.f};
            if (row < N) v = *(const float4*)(A + (size_t)row * K + k0 + 4 * c);
            *(float4*)&As[r][4 * c] = v;
        }
        __syncthreads();
#pragma unroll 4
        for (int k = 0; k < 64; k++) {
            float4 w = *(const float4*)&Ws[k * HID + 4 * tx];
#pragma unroll
            for (int i = 0; i < 4; i++) {
                float a = As[4 * ty + i][k];
                acc[i][0] = fmaf(a, w.x, acc[i][0]);
                acc[i][1] = fmaf(a, w.y, acc[i][1]);
                acc[i][2] = fmaf(a, w.z, acc[i][2]);
                acc[i][3] = fmaf(a, w.w, acc[i][3]);
            }
        }
    }
#pragma unroll
    for (int i = 0; i < 4; i++) {
        int row = row0 + 4 * ty + i;
        if (row < N) {
            float4 v = {acc[i][0], acc[i][1], acc[i][2], acc[i][3]};
            *(float4*)&out[(size_t)row * HID + 4 * tx] = v;
        }
    }
}

// ---- aggregation --------------------------------------------------------

__global__ void k_agg(const float* __restrict__ tin, float* __restrict__ out,
                      const int* __restrict__ rs, const int* __restrict__ deg,
                      const int* __restrict__ col,
                      const float* __restrict__ dinv, const float* __restrict__ bias,
                      int N, int relu) {
    int node = (blockIdx.x * blockDim.x + threadIdx.x) >> 4;
    int l = threadIdx.x & 15;
    if (node >= N) return;
    float di = dinv[node];
    float4 t = ((const float4*)(tin + (size_t)node * HID))[l];
    float s2 = di * di;
    float ax = s2 * t.x, ay = s2 * t.y, az = s2 * t.z, aw = s2 * t.w;

    int beg = rs[node];
    int cnt = deg[node];
    int e = 0;
    for (; e + 4 <= cnt; e += 4) {
        int s0 = col[beg + e], s1 = col[beg + e + 1];
        int sA = col[beg + e + 2], sB = col[beg + e + 3];
        float w0 = dinv[s0] * di, w1 = dinv[s1] * di;
        float w2 = dinv[sA] * di, w3 = dinv[sB] * di;
        float4 v0 = ((const float4*)(tin + (size_t)s0 * HID))[l];
        float4 v1 = ((const float4*)(tin + (size_t)s1 * HID))[l];
        float4 v2 = ((const float4*)(tin + (size_t)sA * HID))[l];
        float4 v3 = ((const float4*)(tin + (size_t)sB * HID))[l];
        ax = fmaf(w0, v0.x, ax); ay = fmaf(w0, v0.y, ay); az = fmaf(w0, v0.z, az); aw = fmaf(w0, v0.w, aw);
        ax = fmaf(w1, v1.x, ax); ay = fmaf(w1, v1.y, ay); az = fmaf(w1, v1.z, az); aw = fmaf(w1, v1.w, aw);
        ax = fmaf(w2, v2.x, ax); ay = fmaf(w2, v2.y, ay); az = fmaf(w2, v2.z, az); aw = fmaf(w2, v2.w, aw);
        ax = fmaf(w3, v3.x, ax); ay = fmaf(w3, v3.y, ay); az = fmaf(w3, v3.z, az); aw = fmaf(w3, v3.w, aw);
    }
    for (; e < cnt; e++) {
        int s = col[beg + e];
        float w = dinv[s] * di;
        float4 v = ((const float4*)(tin + (size_t)s * HID))[l];
        ax = fmaf(w, v.x, ax); ay = fmaf(w, v.y, ay); az = fmaf(w, v.z, az); aw = fmaf(w, v.w, aw);
    }
    float4 b = ((const float4*)bias)[l];
    ax += b.x; ay += b.y; az += b.z; aw += b.w;
    if (relu) {
        ax = fmaxf(ax, 0.f); ay = fmaxf(ay, 0.f);
        az = fmaxf(az, 0.f); aw = fmaxf(aw, 0.f);
    }
    float4 o = {ax, ay, az, aw};
    ((float4*)(out + (size_t)node * HID))[l] = o;
}

// ---- fused mean-pool + centroid-distance head ---------------------------

__global__ void k_pool_head(const float* __restrict__ h, const int* __restrict__ batch,
                            const float* __restrict__ cent, const float* __restrict__ rbias,
                            float* __restrict__ out, int N) {
    int g = blockIdx.x;
    int lo = 0, hi = N;
    while (lo < hi) { int mid = (lo + hi) >> 1; if (batch[mid] < g) lo = mid + 1; else hi = mid; }
    int s = lo;
    lo = 0; hi = N;
    while (lo < hi) { int mid = (lo + hi) >> 1; if (batch[mid] < g + 1) lo = mid + 1; else hi = mid; }
    int e = lo;

    __shared__ float part[4][HID];
    __shared__ float embS[HID];
    __shared__ float dS[NCENTS];
    __shared__ float dpcS[NCLS];

    int lane = threadIdx.x & 63, wid = threadIdx.x >> 6;
    float acc = 0.0f;
    for (int i = s + wid; i < e; i += 4) acc += h[(size_t)i * HID + lane];
    part[wid][lane] = acc;
    __syncthreads();
    if (wid == 0) {
        float v = part[0][lane] + part[1][lane] + part[2][lane] + part[3][lane];
        embS[lane] = v / fmaxf((float)(e - s), 1.0f);
    }
    __syncthreads();
    if (threadIdx.x < NCENTS) {
        const float* c = cent + threadIdx.x * HID;
        float d = 0.0f;
        for (int k = 0; k < HID; k++) { float df = embS[k] - c[k]; d = fmaf(df, df, d); }
        dS[threadIdx.x] = d;
    }
    __syncthreads();
    if (threadIdx.x < NCLS) {
        float m = fminf(dS[threadIdx.x * 3],
                        fminf(dS[threadIdx.x * 3 + 1], dS[threadIdx.x * 3 + 2]));
        dpcS[threadIdx.x] = m;
        out[g * (NCLS + 1) + threadIdx.x] = -m;
    }
    __syncthreads();
    if (threadIdx.x == 0) {
        float m = dpcS[0];
        for (int i = 1; i < NCLS; i++) m = fminf(m, dpcS[i]);
        out[g * (NCLS + 1) + NCLS] = m - rbias[0];
    }
}

// ---- launch -------------------------------------------------------------

extern "C" void kernel_launch(void* const* d_in, const int* in_sizes, int n_in,
                              void* d_out, int out_size, void* d_ws, size_t ws_size,
                              hipStream_t stream) {
    const float* x    = (const float*)d_in[0];
    const int*   ei   = (const int*)d_in[1];   // [2, E]: row0 = src, row1 = dst
    const int*   bat  = (const int*)d_in[2];
    const float* W1   = (const float*)d_in[3];
    const float* b1   = (const float*)d_in[4];
    const float* W2   = (const float*)d_in[5];
    const float* b2   = (const float*)d_in[6];
    const float* W3   = (const float*)d_in[7];
    const float* b3   = (const float*)d_in[8];
    const float* cent = (const float*)d_in[9];
    const float* rb   = (const float*)d_in[10];
    float* out = (float*)d_out;

    const int N = in_sizes[0] / 128;
    const int E = in_sizes[1] / 2;
    const int partSize = ceil_div(N, NPART);
    const int B1 = ceil_div(N, 1024);

    char* p = (char*)d_ws;
    float* A     = (float*)p; p += (size_t)N * HID * 4;
    float* Bb    = (float*)p; p += (size_t)N * HID * 4;
    float* dinv  = (float*)p; p += (size_t)N * 4;
    int*   col   = (int*)p;   p += (size_t)E * 4;
    int*   rs    = (int*)p;   p += (size_t)N * 4;
    int*   bsum  = (int*)p;   p += (size_t)B1 * 4;
    // zeroed region: deg[N] | cursor[N]
    int*   deg   = (int*)p;   p += (size_t)N * 4;
    int*   cur   = (int*)p;   p += (size_t)N * 4;

    hipMemsetAsync(deg, 0, (size_t)2 * N * 4, stream);

    const int nchunk = ceil_div(E, 256);
    k_deg<<<nchunk * NPART, 256, 0, stream>>>(ei + E, deg, E, partSize, N);
    k_scan1<<<B1, 256, 0, stream>>>(deg, bsum, N);
    k_scan2<<<1, 64, 0, stream>>>(bsum, B1);
    k_scan3<<<B1, 256, 0, stream>>>(deg, bsum, rs, dinv, N);
    k_fill<<<nchunk * NPART, 256, 0, stream>>>(ei, ei + E, rs, cur, col, E, partSize, N);

    k_gemm<128><<<ceil_div(N, 64), 256, 0, stream>>>(x, W1, A, N);
    k_agg<<<ceil_div(N * 16, 256), 256, 0, stream>>>(A, Bb, rs, deg, col, dinv, b1, N, 1);
    k_gemm<64><<<ceil_div(N, 64), 256, 0, stream>>>(Bb, W2, A, N);
    k_agg<<<ceil_div(N * 16, 256), 256, 0, stream>>>(A, Bb, rs, deg, col, dinv, b2, N, 1);
    k_gemm<64><<<ceil_div(N, 64), 256, 0, stream>>>(Bb, W3, A, N);
    k_agg<<<ceil_div(N * 16, 256), 256, 0, stream>>>(A, Bb, rs, deg, col, dinv, b3, N, 0);

    k_pool_head<<<1024, 256, 0, stream>>>(Bb, bat, cent, rb, out, N);
}